// Round 6
// baseline (272.157 us; speedup 1.0000x reference)
//
#include <hip/hip_runtime.h>
#include <math.h>

#define BB   16384
#define OBS  512
#define NE   16
#define ACTD 256
#define TK   4

// ---------------- ws layout (as round 5, proven ≥ 91 MB) ----------------
#define WS_ROWLIST_OFF  ((size_t)64)
#define WS_PROBLIST_OFF (WS_ROWLIST_OFF + (size_t)NE * BB * 4)
#define WS_SLOT_OFF     (WS_PROBLIST_OFF + (size_t)NE * BB * 4)
#define WS_XBF_OFF      (WS_SLOT_OFF + (size_t)NE * BB * 4)
#define WS_WM_OFF       (WS_XBF_OFF + (size_t)BB * OBS * 2)
#define WS_WL_OFF       (WS_WM_OFF + (size_t)NE * ACTD * OBS * 2)
#define WS_PART_OFF     (WS_WL_OFF + (size_t)NE * ACTD * OBS * 2)
#define WS_NEEDED_A2    (WS_PART_OFF + (size_t)2 * BB * TK * ACTD * 2)

typedef __attribute__((ext_vector_type(8))) short short8;
typedef __attribute__((ext_vector_type(4))) float floatx4;

__device__ __forceinline__ ushort f2bf(float f) {
    union { float f; unsigned u; } v; v.f = f;
    unsigned r = v.u + 0x7fffu + ((v.u >> 16) & 1u);
    return (ushort)(r >> 16);
}
__device__ __forceinline__ float bf2f(ushort u) {
    union { unsigned u; float f; } v; v.u = ((unsigned)u) << 16;
    return v.f;
}
// -5 + 3.5*(tanh(v)+1) == -5 + 7/(1+exp(-2v))
__device__ __forceinline__ float lstd_act(float v) {
    return -5.f + 7.f * __builtin_amdgcn_rcpf(1.f + __expf(-2.f * v));
}

// -------------------------------------------------------------------------
// fp32 -> bf16 conversion (weights)
// -------------------------------------------------------------------------
__global__ __launch_bounds__(256) void cvt_bf16(const float* __restrict__ src,
                                                ushort* __restrict__ dst, int n4)
{
    const int i = blockIdx.x * 256 + threadIdx.x;
    if (i >= n4) return;
    float4 v = ((const float4*)src)[i];
    ushort4 o;
    o.x = f2bf(v.x); o.y = f2bf(v.y); o.z = f2bf(v.z); o.w = f2bf(v.w);
    ((ushort4*)dst)[i] = o;
}

// -------------------------------------------------------------------------
// Router v2: quarter-wave per row (16 rows/block). Each lane holds 32
// x-elements in registers; per expert: 8 broadcast LDS b128 W-reads +
// 32 FMA + 4-step 16-lane butterfly. fp32 logic (matches reference).
// -------------------------------------------------------------------------
__global__ __launch_bounds__(256) void router_kernel(
    const float* __restrict__ x, const float* __restrict__ rw,
    const float* __restrict__ rb,
    int* __restrict__ counts, int* __restrict__ rowlist,
    float* __restrict__ problist, int* __restrict__ slot_of,
    ushort* __restrict__ xbf, int do_aux)
{
    __shared__ float wlds[NE * OBS];
    __shared__ int   lcnt[NE], lbase[NE];
    __shared__ int   s_e[64], s_lpos[64];
    __shared__ float s_p[64];

    const float4* rw4 = (const float4*)rw;
    float4* wl4 = (float4*)wlds;
    #pragma unroll
    for (int i = 0; i < 8; ++i) wl4[threadIdx.x + 256 * i] = rw4[threadIdx.x + 256 * i];
    if (threadIdx.x < NE) lcnt[threadIdx.x] = 0;
    __syncthreads();

    const int wave = threadIdx.x >> 6;
    const int lane = threadIdx.x & 63;
    const int q    = lane >> 4;     // row within quad
    const int i16  = lane & 15;     // element-chunk / writer id
    const int row  = blockIdx.x * 16 + wave * 4 + q;

    // x row into registers: lane covers cols {64s + 4*i16 .. +4}, s=0..7
    const float4* xr = (const float4*)(x + (size_t)row * OBS);
    float4 xv[8];
    #pragma unroll
    for (int s = 0; s < 8; ++s) xv[s] = xr[s * 16 + i16];

    if (do_aux) {
        ushort4* xo = (ushort4*)(xbf + (size_t)row * OBS);
        #pragma unroll
        for (int s = 0; s < 8; ++s) {
            ushort4 o;
            o.x = f2bf(xv[s].x); o.y = f2bf(xv[s].y);
            o.z = f2bf(xv[s].z); o.w = f2bf(xv[s].w);
            xo[s * 16 + i16] = o;
        }
    }

    float p[NE];
    float m = -1e30f;
    #pragma unroll
    for (int e = 0; e < NE; ++e) {
        const float4* wep = (const float4*)(wlds + e * OBS);
        float d = 0.f;
        #pragma unroll
        for (int s = 0; s < 8; ++s) {
            float4 wv = wep[s * 16 + i16];
            d += xv[s].x * wv.x + xv[s].y * wv.y + xv[s].z * wv.z + xv[s].w * wv.w;
        }
        d += __shfl_xor(d, 1, 64);
        d += __shfl_xor(d, 2, 64);
        d += __shfl_xor(d, 4, 64);
        d += __shfl_xor(d, 8, 64);
        d += rb[e];
        p[e] = d;
        m = fmaxf(m, d);
    }
    float s = 0.f;
    #pragma unroll
    for (int e = 0; e < NE; ++e) { p[e] = __expf(p[e] - m); s += p[e]; }
    const float inv = 1.f / s;
    #pragma unroll
    for (int e = 0; e < NE; ++e) p[e] *= inv;

    int   sel_e[TK];
    float sel_p[TK];
    #pragma unroll
    for (int k = 0; k < TK; ++k) {
        float best = -1.f; int be = 0;
        #pragma unroll
        for (int e = 0; e < NE; ++e)
            if (p[e] > best) { best = p[e]; be = e; }
        sel_e[k] = be; sel_p[k] = best;
        #pragma unroll
        for (int e = 0; e < NE; ++e)
            if (e == be) p[e] = -2.f;
    }
    if (i16 < TK) {
        const int e = sel_e[i16];
        const int lpos = atomicAdd(&lcnt[e], 1);   // LDS atomic
        const int sid = (wave * 4 + q) * 4 + i16;
        s_e[sid] = e; s_p[sid] = sel_p[i16]; s_lpos[sid] = lpos;
    }
    __syncthreads();
    if (threadIdx.x < NE)
        lbase[threadIdx.x] = atomicAdd(&counts[threadIdx.x], lcnt[threadIdx.x]);
    __syncthreads();
    if (threadIdx.x < 64) {
        const int sid = threadIdx.x;
        const int e   = s_e[sid];
        const int pos = lbase[e] + s_lpos[sid];
        const int grow = blockIdx.x * 16 + (sid >> 2);
        rowlist[e * BB + pos]  = grow;
        problist[e * BB + pos] = s_p[sid];
        if (do_aux) slot_of[e * BB + pos] = grow * TK + (sid & 3);
    }
}

// -------------------------------------------------------------------------
// Fused expert-grouped bf16 MFMA GEMM. grid = (128 row-tiles, 16, 2 planes)
// Block: 128 rows x 256 cols (full ACT). BK=64. 4 waves 2x2, wave = 64x128
// (4x8 MFMA tiles, acc = 32 floatx4). x staged ONCE per K-iter for all 256
// output cols. XOR-swizzled LDS (proven conflict-free). Non-atomic bf16
// partial stores (slot-indexed).
// -------------------------------------------------------------------------
__global__ __launch_bounds__(256) void moe_gemm_fused(
    const ushort* __restrict__ xbf,
    const ushort* __restrict__ wmean, const ushort* __restrict__ wlstd,
    const float* __restrict__ mean_b, const float* __restrict__ lstd_b,
    const int* __restrict__ counts, const int* __restrict__ rowlist,
    const float* __restrict__ problist, const int* __restrict__ slot_of,
    ushort* __restrict__ partial)
{
    const int e   = blockIdx.y;
    const int cnt = counts[e];
    const int tile0 = blockIdx.x * 128;
    if (tile0 >= cnt) return;

    const int which = blockIdx.z;
    const ushort* W   = (which ? wlstd : wmean) + (size_t)e * ACTD * OBS;
    const float* bias = (which ? lstd_b : mean_b) + e * ACTD;
    ushort* Pp = partial + (size_t)which * BB * TK * ACTD;

    __shared__ __align__(16) ushort xls[128 * 64];   // 16 KB
    __shared__ __align__(16) ushort wls[256 * 64];   // 32 KB
    __shared__ int   idx_l[128];
    __shared__ float probs_l[128];

    const int tid = threadIdx.x;
    const int l   = tid & 63;
    const int w   = tid >> 6;

    if (tid < 128) {
        const int pos = tile0 + tid;
        const bool v = pos < cnt;
        probs_l[tid] = v ? problist[e * BB + pos] : 0.f;
        idx_l[tid]   = v ? slot_of[e * BB + pos] : -1;
    }

    const int c_sw = (l & 7) ^ (l >> 3);
    const ushort* xptr[4];
    const ushort* wptr[8];
    #pragma unroll
    for (int i = 0; i < 4; ++i) {
        const int lrow = 32 * w + 8 * i + (l >> 3);
        const int pos  = tile0 + lrow;
        const int grow = (pos < cnt) ? rowlist[e * BB + pos] : rowlist[e * BB + tile0];
        xptr[i] = xbf + (size_t)grow * OBS + c_sw * 8;
    }
    #pragma unroll
    for (int j = 0; j < 8; ++j) {
        const int wcol = 64 * w + 8 * j + (l >> 3);
        wptr[j] = W + (size_t)wcol * OBS + c_sw * 8;
    }

    const int wr  = w >> 1;          // row-half (64)
    const int wc  = w & 1;           // col-half (128)
    const int rlo = l & 15;
    const int q   = l >> 4;
    const int r7  = rlo & 7;

    floatx4 acc[4][8];
    #pragma unroll
    for (int mi = 0; mi < 4; ++mi)
        #pragma unroll
        for (int ni = 0; ni < 8; ++ni)
            acc[mi][ni] = (floatx4){0.f, 0.f, 0.f, 0.f};

    for (int kt = 0; kt < OBS; kt += 64) {
        __syncthreads();
        #pragma unroll
        for (int i = 0; i < 4; ++i)
            __builtin_amdgcn_global_load_lds(
                (const __attribute__((address_space(1))) unsigned int*)(xptr[i] + kt),
                (__attribute__((address_space(3))) unsigned int*)(xls + (4 * w + i) * 512),
                16, 0, 0);
        #pragma unroll
        for (int j = 0; j < 8; ++j)
            __builtin_amdgcn_global_load_lds(
                (const __attribute__((address_space(1))) unsigned int*)(wptr[j] + kt),
                (__attribute__((address_space(3))) unsigned int*)(wls + (8 * w + j) * 512),
                16, 0, 0);
        __syncthreads();

        #pragma unroll
        for (int ks = 0; ks < 2; ++ks) {
            const int ch = (4 * ks + q) ^ r7;
            short8 af[4], bfr[8];
            #pragma unroll
            for (int mi = 0; mi < 4; ++mi)
                af[mi] = *(const short8*)(xls + (wr * 64 + mi * 16 + rlo) * 64 + ch * 8);
            #pragma unroll
            for (int ni = 0; ni < 8; ++ni)
                bfr[ni] = *(const short8*)(wls + (wc * 128 + ni * 16 + rlo) * 64 + ch * 8);
            #pragma unroll
            for (int mi = 0; mi < 4; ++mi)
                #pragma unroll
                for (int ni = 0; ni < 8; ++ni)
                    acc[mi][ni] = __builtin_amdgcn_mfma_f32_16x16x32_bf16(
                        af[mi], bfr[ni], acc[mi][ni], 0, 0, 0);
        }
    }

    #pragma unroll
    for (int mi = 0; mi < 4; ++mi) {
        #pragma unroll
        for (int r = 0; r < 4; ++r) {
            const int lrow = wr * 64 + mi * 16 + q * 4 + r;
            const int slot = idx_l[lrow];
            if (slot < 0) continue;
            const float pw = probs_l[lrow];
            ushort* orow = Pp + (size_t)slot * ACTD + wc * 128 + rlo;
            #pragma unroll
            for (int ni = 0; ni < 8; ++ni)
                orow[ni * 16] = f2bf(pw * (acc[mi][ni][r] + bias[wc * 128 + ni * 16 + rlo]));
        }
    }
}

// -------------------------------------------------------------------------
// Combine: out[r] = sum_k partial[r*4+k]; fast sigmoid-form activation.
// -------------------------------------------------------------------------
__global__ __launch_bounds__(256) void combine_kernel(
    const ushort* __restrict__ partial, float* __restrict__ out)
{
    const int t  = blockIdx.x * 256 + threadIdx.x;   // BB*64 threads
    const int r  = t >> 6;
    const int c4 = (t & 63) * 4;
    const ushort* Pm = partial;
    const ushort* Pl = partial + (size_t)BB * TK * ACTD;

    float m0 = 0.f, m1 = 0.f, m2 = 0.f, m3 = 0.f;
    float l0 = 0.f, l1 = 0.f, l2 = 0.f, l3 = 0.f;
    #pragma unroll
    for (int k = 0; k < TK; ++k) {
        const size_t off = (size_t)(r * TK + k) * ACTD + c4;
        ushort4 vm = *(const ushort4*)(Pm + off);
        ushort4 vl = *(const ushort4*)(Pl + off);
        m0 += bf2f(vm.x); m1 += bf2f(vm.y); m2 += bf2f(vm.z); m3 += bf2f(vm.w);
        l0 += bf2f(vl.x); l1 += bf2f(vl.y); l2 += bf2f(vl.z); l3 += bf2f(vl.w);
    }
    float4 mo = make_float4(m0, m1, m2, m3);
    float4 lo = make_float4(lstd_act(l0), lstd_act(l1), lstd_act(l2), lstd_act(l3));
    *(float4*)(out + (size_t)r * ACTD + c4) = mo;
    *(float4*)(out + (size_t)BB * ACTD + (size_t)r * ACTD + c4) = lo;
}

// -------------------------------------------------------------------------
// Tier B: fp32 expert-grouped GEMM (round-1, proven fallback).
// -------------------------------------------------------------------------
__global__ __launch_bounds__(256) void moe_gemm_f32(
    const float* __restrict__ x,
    const float* __restrict__ mean_w, const float* __restrict__ mean_b,
    const float* __restrict__ lstd_w, const float* __restrict__ lstd_b,
    const int* __restrict__ counts, const int* __restrict__ rowlist,
    const float* __restrict__ problist, float* __restrict__ out)
{
    const int e = blockIdx.y;
    const int cnt = counts[e];
    const int tile0 = blockIdx.x * 32;
    if (tile0 >= cnt) return;

    const int zz    = blockIdx.z;
    const int which = zz >> 1;
    const int ctile = (zz & 1) * 128;
    const float* W    = (which ? lstd_w : mean_w) + (size_t)e * ACTD * OBS;
    const float* bias = (which ? lstd_b : mean_b) + e * ACTD;
    float* outp = out + (size_t)which * BB * ACTD;

    __shared__ float xls[32][32];
    __shared__ float wls[32][128];

    const int sr  = threadIdx.x >> 3;
    const int skq = threadIdx.x & 7;
    int stage_row = -1;
    {
        const int pos = tile0 + sr;
        if (pos < cnt) stage_row = rowlist[e * BB + pos];
    }

    const int r0 = (threadIdx.x >> 5) << 2;
    const int c0 = (threadIdx.x & 31) << 2;

    float acc[4][4] = {};

    for (int kt = 0; kt < OBS; kt += 32) {
        __syncthreads();
        {
            float4 v = make_float4(0.f, 0.f, 0.f, 0.f);
            if (stage_row >= 0)
                v = *(const float4*)(x + (size_t)stage_row * OBS + kt + skq * 4);
            xls[skq * 4 + 0][sr] = v.x;
            xls[skq * 4 + 1][sr] = v.y;
            xls[skq * 4 + 2][sr] = v.z;
            xls[skq * 4 + 3][sr] = v.w;
        }
        #pragma unroll
        for (int j = 0; j < 4; ++j) {
            const int i  = threadIdx.x + 256 * j;
            const int c  = i >> 3;
            const int kq = i & 7;
            float4 v = *(const float4*)(W + (size_t)(ctile + c) * OBS + kt + kq * 4);
            wls[kq * 4 + 0][c] = v.x;
            wls[kq * 4 + 1][c] = v.y;
            wls[kq * 4 + 2][c] = v.z;
            wls[kq * 4 + 3][c] = v.w;
        }
        __syncthreads();

        #pragma unroll
        for (int k = 0; k < 32; ++k) {
            const float4 xa = *(const float4*)&xls[k][r0];
            const float4 wb = *(const float4*)&wls[k][c0];
            const float xv[4] = { xa.x, xa.y, xa.z, xa.w };
            const float wv[4] = { wb.x, wb.y, wb.z, wb.w };
            #pragma unroll
            for (int i = 0; i < 4; ++i)
                #pragma unroll
                for (int j = 0; j < 4; ++j)
                    acc[i][j] = fmaf(xv[i], wv[j], acc[i][j]);
        }
    }

    #pragma unroll
    for (int i = 0; i < 4; ++i) {
        const int pos = tile0 + r0 + i;
        if (pos >= cnt) break;
        const int grow = rowlist[e * BB + pos];
        const float pw = problist[e * BB + pos];
        float* orow = outp + (size_t)grow * ACTD + ctile + c0;
        #pragma unroll
        for (int j = 0; j < 4; ++j)
            atomicAdd(&orow[j], pw * (acc[i][j] + bias[ctile + c0 + j]));
    }
}

__global__ __launch_bounds__(256) void tanh_ep(float* __restrict__ out)
{
    const int i = blockIdx.x * 256 + threadIdx.x;
    float4* p = (float4*)(out + (size_t)BB * ACTD);
    float4 v = p[i];
    v.x = -5.f + 3.5f * (tanhf(v.x) + 1.f);
    v.y = -5.f + 3.5f * (tanhf(v.y) + 1.f);
    v.z = -5.f + 3.5f * (tanhf(v.z) + 1.f);
    v.w = -5.f + 3.5f * (tanhf(v.w) + 1.f);
    p[i] = v;
}

extern "C" void kernel_launch(void* const* d_in, const int* in_sizes, int n_in,
                              void* d_out, int out_size, void* d_ws, size_t ws_size,
                              hipStream_t stream)
{
    const float* x        = (const float*)d_in[0];
    const float* router_w = (const float*)d_in[1];
    const float* router_b = (const float*)d_in[2];
    const float* mean_w   = (const float*)d_in[3];
    const float* mean_b   = (const float*)d_in[4];
    const float* lstd_w   = (const float*)d_in[5];
    const float* lstd_b   = (const float*)d_in[6];

    float* out = (float*)d_out;
    int*    counts   = (int*)d_ws;
    int*    rowlist  = (int*)((char*)d_ws + WS_ROWLIST_OFF);
    float*  problist = (float*)((char*)d_ws + WS_PROBLIST_OFF);
    int*    slot_of  = (int*)((char*)d_ws + WS_SLOT_OFF);
    ushort* xbf      = (ushort*)((char*)d_ws + WS_XBF_OFF);
    ushort* wmbf     = (ushort*)((char*)d_ws + WS_WM_OFF);
    ushort* wlbf     = (ushort*)((char*)d_ws + WS_WL_OFF);
    ushort* partial  = (ushort*)((char*)d_ws + WS_PART_OFF);

    const bool tierA2 = (ws_size >= WS_NEEDED_A2);

    hipMemsetAsync(d_ws, 0, 64, stream);

    if (tierA2) {
        const int wn4 = NE * ACTD * OBS / 4;
        cvt_bf16<<<(wn4 + 255) / 256, 256, 0, stream>>>(mean_w, wmbf, wn4);
        cvt_bf16<<<(wn4 + 255) / 256, 256, 0, stream>>>(lstd_w, wlbf, wn4);

        router_kernel<<<BB / 16, 256, 0, stream>>>(x, router_w, router_b,
                                                   counts, rowlist, problist,
                                                   slot_of, xbf, 1);

        dim3 grid(BB / 128, NE, 2);
        moe_gemm_fused<<<grid, 256, 0, stream>>>(xbf, wmbf, wlbf, mean_b, lstd_b,
                                                 counts, rowlist, problist,
                                                 slot_of, partial);
        combine_kernel<<<BB * 64 / 256, 256, 0, stream>>>(partial, out);
    } else {
        hipMemsetAsync(d_out, 0, (size_t)out_size * sizeof(float), stream);
        router_kernel<<<BB / 16, 256, 0, stream>>>(x, router_w, router_b,
                                                   counts, rowlist, problist,
                                                   (int*)nullptr, (ushort*)nullptr, 0);
        dim3 grid(BB / 32, NE, 4);
        moe_gemm_f32<<<grid, 256, 0, stream>>>(x, mean_w, mean_b, lstd_w, lstd_b,
                                               counts, rowlist, problist, out);
        tanh_ep<<<(BB * ACTD / 4) / 256, 256, 0, stream>>>(out);
    }
}

// Round 7
// 220.774 us; speedup vs baseline: 1.2327x; 1.2327x over previous
//
#include <hip/hip_runtime.h>
#include <math.h>

#define BB   16384
#define OBS  512
#define NE   16
#define ACTD 256
#define TK   4

// ---------------- ws layout (as round 5, proven ≥ 91 MB) ----------------
#define WS_ROWLIST_OFF  ((size_t)64)
#define WS_PROBLIST_OFF (WS_ROWLIST_OFF + (size_t)NE * BB * 4)
#define WS_SLOT_OFF     (WS_PROBLIST_OFF + (size_t)NE * BB * 4)
#define WS_XBF_OFF      (WS_SLOT_OFF + (size_t)NE * BB * 4)
#define WS_WM_OFF       (WS_XBF_OFF + (size_t)BB * OBS * 2)
#define WS_WL_OFF       (WS_WM_OFF + (size_t)NE * ACTD * OBS * 2)
#define WS_PART_OFF     (WS_WL_OFF + (size_t)NE * ACTD * OBS * 2)
#define WS_NEEDED_A2    (WS_PART_OFF + (size_t)2 * BB * TK * ACTD * 2)

typedef __attribute__((ext_vector_type(8))) short short8;
typedef __attribute__((ext_vector_type(4))) float floatx4;

__device__ __forceinline__ ushort f2bf(float f) {
    union { float f; unsigned u; } v; v.f = f;
    unsigned r = v.u + 0x7fffu + ((v.u >> 16) & 1u);
    return (ushort)(r >> 16);
}
__device__ __forceinline__ float bf2f(ushort u) {
    union { unsigned u; float f; } v; v.u = ((unsigned)u) << 16;
    return v.f;
}
// -5 + 3.5*(tanh(v)+1) == -5 + 7/(1+exp(-2v))
__device__ __forceinline__ float lstd_act(float v) {
    return -5.f + 7.f * __builtin_amdgcn_rcpf(1.f + __expf(-2.f * v));
}

// -------------------------------------------------------------------------
// Both weight tensors -> bf16 in ONE launch; also zeroes the 16 counters.
// -------------------------------------------------------------------------
__global__ __launch_bounds__(256) void cvt2_bf16(
    const float* __restrict__ s0, const float* __restrict__ s1,
    ushort* __restrict__ d0, ushort* __restrict__ d1, int n4,
    int* __restrict__ counts)
{
    if (blockIdx.x == 0 && threadIdx.x < NE) counts[threadIdx.x] = 0;
    const int i = blockIdx.x * 256 + threadIdx.x;
    const float4* src = (i < n4) ? ((const float4*)s0 + i) : ((const float4*)s1 + (i - n4));
    ushort4* dst = (i < n4) ? ((ushort4*)d0 + i) : ((ushort4*)d1 + (i - n4));
    float4 v = *src;
    ushort4 o;
    o.x = f2bf(v.x); o.y = f2bf(v.y); o.z = f2bf(v.z); o.w = f2bf(v.w);
    *dst = o;
}

// -------------------------------------------------------------------------
// Router v2: quarter-wave per row (16 rows/block). fp32 routing logic.
// -------------------------------------------------------------------------
__global__ __launch_bounds__(256) void router_kernel(
    const float* __restrict__ x, const float* __restrict__ rw,
    const float* __restrict__ rb,
    int* __restrict__ counts, int* __restrict__ rowlist,
    float* __restrict__ problist, int* __restrict__ slot_of,
    ushort* __restrict__ xbf, int do_aux)
{
    __shared__ float wlds[NE * OBS];
    __shared__ int   lcnt[NE], lbase[NE];
    __shared__ int   s_e[64], s_lpos[64];
    __shared__ float s_p[64];

    const float4* rw4 = (const float4*)rw;
    float4* wl4 = (float4*)wlds;
    #pragma unroll
    for (int i = 0; i < 8; ++i) wl4[threadIdx.x + 256 * i] = rw4[threadIdx.x + 256 * i];
    if (threadIdx.x < NE) lcnt[threadIdx.x] = 0;
    __syncthreads();

    const int wave = threadIdx.x >> 6;
    const int lane = threadIdx.x & 63;
    const int q    = lane >> 4;
    const int i16  = lane & 15;
    const int row  = blockIdx.x * 16 + wave * 4 + q;

    const float4* xr = (const float4*)(x + (size_t)row * OBS);
    float4 xv[8];
    #pragma unroll
    for (int s = 0; s < 8; ++s) xv[s] = xr[s * 16 + i16];

    if (do_aux) {
        ushort4* xo = (ushort4*)(xbf + (size_t)row * OBS);
        #pragma unroll
        for (int s = 0; s < 8; ++s) {
            ushort4 o;
            o.x = f2bf(xv[s].x); o.y = f2bf(xv[s].y);
            o.z = f2bf(xv[s].z); o.w = f2bf(xv[s].w);
            xo[s * 16 + i16] = o;
        }
    }

    float p[NE];
    float m = -1e30f;
    #pragma unroll
    for (int e = 0; e < NE; ++e) {
        const float4* wep = (const float4*)(wlds + e * OBS);
        float d = 0.f;
        #pragma unroll
        for (int s = 0; s < 8; ++s) {
            float4 wv = wep[s * 16 + i16];
            d += xv[s].x * wv.x + xv[s].y * wv.y + xv[s].z * wv.z + xv[s].w * wv.w;
        }
        d += __shfl_xor(d, 1, 64);
        d += __shfl_xor(d, 2, 64);
        d += __shfl_xor(d, 4, 64);
        d += __shfl_xor(d, 8, 64);
        d += rb[e];
        p[e] = d;
        m = fmaxf(m, d);
    }
    float s = 0.f;
    #pragma unroll
    for (int e = 0; e < NE; ++e) { p[e] = __expf(p[e] - m); s += p[e]; }
    const float inv = 1.f / s;
    #pragma unroll
    for (int e = 0; e < NE; ++e) p[e] *= inv;

    int   sel_e[TK];
    float sel_p[TK];
    #pragma unroll
    for (int k = 0; k < TK; ++k) {
        float best = -1.f; int be = 0;
        #pragma unroll
        for (int e = 0; e < NE; ++e)
            if (p[e] > best) { best = p[e]; be = e; }
        sel_e[k] = be; sel_p[k] = best;
        #pragma unroll
        for (int e = 0; e < NE; ++e)
            if (e == be) p[e] = -2.f;
    }
    if (i16 < TK) {
        const int e = sel_e[i16];
        const int lpos = atomicAdd(&lcnt[e], 1);
        const int sid = (wave * 4 + q) * 4 + i16;
        s_e[sid] = e; s_p[sid] = sel_p[i16]; s_lpos[sid] = lpos;
    }
    __syncthreads();
    if (threadIdx.x < NE)
        lbase[threadIdx.x] = atomicAdd(&counts[threadIdx.x], lcnt[threadIdx.x]);
    __syncthreads();
    if (threadIdx.x < 64) {
        const int sid = threadIdx.x;
        const int e   = s_e[sid];
        const int pos = lbase[e] + s_lpos[sid];
        const int grow = blockIdx.x * 16 + (sid >> 2);
        rowlist[e * BB + pos]  = grow;
        problist[e * BB + pos] = s_p[sid];
        if (do_aux) slot_of[e * BB + pos] = grow * TK + (sid & 3);
    }
}

// -------------------------------------------------------------------------
// Expert-grouped bf16 MFMA GEMM, 64x128 tile. grid = (256 row-tiles, 16, 4)
//   z bit0: 128-col half, z bit1: plane. BK=64, 4 waves 2x2 (wave = 32x64).
// 24.5 KB LDS -> ~5-6 blocks/CU for latency hiding. XOR-swizzled LDS
// (slot = chunk ^ (row&7)): conflict-free DMA writes + b128 reads.
// Non-atomic bf16 partial stores (slot-indexed).
// -------------------------------------------------------------------------
__global__ __launch_bounds__(256) void moe_gemm_64(
    const ushort* __restrict__ xbf,
    const ushort* __restrict__ wmean, const ushort* __restrict__ wlstd,
    const float* __restrict__ mean_b, const float* __restrict__ lstd_b,
    const int* __restrict__ counts, const int* __restrict__ rowlist,
    const float* __restrict__ problist, const int* __restrict__ slot_of,
    ushort* __restrict__ partial)
{
    const int e   = blockIdx.y;
    const int cnt = counts[e];
    const int tile0 = blockIdx.x * 64;
    if (tile0 >= cnt) return;

    const int zz    = blockIdx.z;
    const int which = zz >> 1;
    const int ctile = (zz & 1) * 128;
    const ushort* W   = (which ? wlstd : wmean) + (size_t)e * ACTD * OBS;
    const float* bias = (which ? lstd_b : mean_b) + e * ACTD + ctile;
    ushort* Pp = partial + (size_t)which * BB * TK * ACTD;

    __shared__ __align__(16) ushort xls[64 * 64];    // 8 KB: 8 windows
    __shared__ __align__(16) ushort wls[128 * 64];   // 16 KB: 16 windows
    __shared__ int   idx_l[64];
    __shared__ float probs_l[64];

    const int tid = threadIdx.x;
    const int l   = tid & 63;
    const int w   = tid >> 6;

    if (tid < 64) {
        const int pos = tile0 + tid;
        const bool v = pos < cnt;
        probs_l[tid] = v ? problist[e * BB + pos] : 0.f;
        idx_l[tid]   = v ? slot_of[e * BB + pos] : -1;
    }

    const int c_sw = (l & 7) ^ (l >> 3);
    // x windows: wave w stages windows {2w, 2w+1} (8 tile-rows each)
    const ushort* xp[2];
    #pragma unroll
    for (int i = 0; i < 2; ++i) {
        const int lrow = 16 * w + 8 * i + (l >> 3);
        const int pos  = tile0 + lrow;
        const int grow = (pos < cnt) ? rowlist[e * BB + pos] : rowlist[e * BB + tile0];
        xp[i] = xbf + (size_t)grow * OBS + c_sw * 8;
    }
    // W windows: wave w stages windows {4w..4w+3} (8 cols each)
    const ushort* wp[4];
    #pragma unroll
    for (int j = 0; j < 4; ++j) {
        const int col = ctile + 32 * w + 8 * j + (l >> 3);
        wp[j] = W + (size_t)col * OBS + c_sw * 8;
    }

    const int wm  = (w >> 1) * 32;   // row-half of 64
    const int wn  = (w & 1) * 64;    // col-half of 128
    const int rlo = l & 15;
    const int q   = l >> 4;
    const int r7  = rlo & 7;

    floatx4 acc[2][4];
    #pragma unroll
    for (int mi = 0; mi < 2; ++mi)
        #pragma unroll
        for (int ni = 0; ni < 4; ++ni)
            acc[mi][ni] = (floatx4){0.f, 0.f, 0.f, 0.f};

    for (int kt = 0; kt < OBS; kt += 64) {
        __syncthreads();
        #pragma unroll
        for (int i = 0; i < 2; ++i)
            __builtin_amdgcn_global_load_lds(
                (const __attribute__((address_space(1))) unsigned int*)(xp[i] + kt),
                (__attribute__((address_space(3))) unsigned int*)(xls + (2 * w + i) * 512),
                16, 0, 0);
        #pragma unroll
        for (int j = 0; j < 4; ++j)
            __builtin_amdgcn_global_load_lds(
                (const __attribute__((address_space(1))) unsigned int*)(wp[j] + kt),
                (__attribute__((address_space(3))) unsigned int*)(wls + (4 * w + j) * 512),
                16, 0, 0);
        __syncthreads();

        #pragma unroll
        for (int ks = 0; ks < 2; ++ks) {
            const int ch = (4 * ks + q) ^ r7;
            short8 af[2], bfr[4];
            #pragma unroll
            for (int mi = 0; mi < 2; ++mi)
                af[mi] = *(const short8*)(xls + (wm + mi * 16 + rlo) * 64 + ch * 8);
            #pragma unroll
            for (int ni = 0; ni < 4; ++ni)
                bfr[ni] = *(const short8*)(wls + (wn + ni * 16 + rlo) * 64 + ch * 8);
            #pragma unroll
            for (int mi = 0; mi < 2; ++mi)
                #pragma unroll
                for (int ni = 0; ni < 4; ++ni)
                    acc[mi][ni] = __builtin_amdgcn_mfma_f32_16x16x32_bf16(
                        af[mi], bfr[ni], acc[mi][ni], 0, 0, 0);
        }
    }

    #pragma unroll
    for (int mi = 0; mi < 2; ++mi) {
        #pragma unroll
        for (int r = 0; r < 4; ++r) {
            const int lrow = wm + mi * 16 + q * 4 + r;
            const int slot = idx_l[lrow];
            if (slot < 0) continue;
            const float pw = probs_l[lrow];
            ushort* orow = Pp + (size_t)slot * ACTD + ctile + wn + rlo;
            #pragma unroll
            for (int ni = 0; ni < 4; ++ni)
                orow[ni * 16] = f2bf(pw * (acc[mi][ni][r] + bias[wn + ni * 16 + rlo]));
        }
    }
}

// -------------------------------------------------------------------------
// Combine: out[r] = sum_k partial[r*4+k]; fast sigmoid-form activation.
// -------------------------------------------------------------------------
__global__ __launch_bounds__(256) void combine_kernel(
    const ushort* __restrict__ partial, float* __restrict__ out)
{
    const int t  = blockIdx.x * 256 + threadIdx.x;
    const int r  = t >> 6;
    const int c4 = (t & 63) * 4;
    const ushort* Pm = partial;
    const ushort* Pl = partial + (size_t)BB * TK * ACTD;

    float m0 = 0.f, m1 = 0.f, m2 = 0.f, m3 = 0.f;
    float l0 = 0.f, l1 = 0.f, l2 = 0.f, l3 = 0.f;
    #pragma unroll
    for (int k = 0; k < TK; ++k) {
        const size_t off = (size_t)(r * TK + k) * ACTD + c4;
        ushort4 vm = *(const ushort4*)(Pm + off);
        ushort4 vl = *(const ushort4*)(Pl + off);
        m0 += bf2f(vm.x); m1 += bf2f(vm.y); m2 += bf2f(vm.z); m3 += bf2f(vm.w);
        l0 += bf2f(vl.x); l1 += bf2f(vl.y); l2 += bf2f(vl.z); l3 += bf2f(vl.w);
    }
    float4 mo = make_float4(m0, m1, m2, m3);
    float4 lo = make_float4(lstd_act(l0), lstd_act(l1), lstd_act(l2), lstd_act(l3));
    *(float4*)(out + (size_t)r * ACTD + c4) = mo;
    *(float4*)(out + (size_t)BB * ACTD + (size_t)r * ACTD + c4) = lo;
}

// -------------------------------------------------------------------------
// Tier B: fp32 expert-grouped GEMM (round-1, proven fallback).
// -------------------------------------------------------------------------
__global__ __launch_bounds__(256) void moe_gemm_f32(
    const float* __restrict__ x,
    const float* __restrict__ mean_w, const float* __restrict__ mean_b,
    const float* __restrict__ lstd_w, const float* __restrict__ lstd_b,
    const int* __restrict__ counts, const int* __restrict__ rowlist,
    const float* __restrict__ problist, float* __restrict__ out)
{
    const int e = blockIdx.y;
    const int cnt = counts[e];
    const int tile0 = blockIdx.x * 32;
    if (tile0 >= cnt) return;

    const int zz    = blockIdx.z;
    const int which = zz >> 1;
    const int ctile = (zz & 1) * 128;
    const float* W    = (which ? lstd_w : mean_w) + (size_t)e * ACTD * OBS;
    const float* bias = (which ? lstd_b : mean_b) + e * ACTD;
    float* outp = out + (size_t)which * BB * ACTD;

    __shared__ float xls[32][32];
    __shared__ float wls[32][128];

    const int sr  = threadIdx.x >> 3;
    const int skq = threadIdx.x & 7;
    int stage_row = -1;
    {
        const int pos = tile0 + sr;
        if (pos < cnt) stage_row = rowlist[e * BB + pos];
    }

    const int r0 = (threadIdx.x >> 5) << 2;
    const int c0 = (threadIdx.x & 31) << 2;

    float acc[4][4] = {};

    for (int kt = 0; kt < OBS; kt += 32) {
        __syncthreads();
        {
            float4 v = make_float4(0.f, 0.f, 0.f, 0.f);
            if (stage_row >= 0)
                v = *(const float4*)(x + (size_t)stage_row * OBS + kt + skq * 4);
            xls[skq * 4 + 0][sr] = v.x;
            xls[skq * 4 + 1][sr] = v.y;
            xls[skq * 4 + 2][sr] = v.z;
            xls[skq * 4 + 3][sr] = v.w;
        }
        #pragma unroll
        for (int j = 0; j < 4; ++j) {
            const int i  = threadIdx.x + 256 * j;
            const int c  = i >> 3;
            const int kq = i & 7;
            float4 v = *(const float4*)(W + (size_t)(ctile + c) * OBS + kt + kq * 4);
            wls[kq * 4 + 0][c] = v.x;
            wls[kq * 4 + 1][c] = v.y;
            wls[kq * 4 + 2][c] = v.z;
            wls[kq * 4 + 3][c] = v.w;
        }
        __syncthreads();

        #pragma unroll
        for (int k = 0; k < 32; ++k) {
            const float4 xa = *(const float4*)&xls[k][r0];
            const float4 wb = *(const float4*)&wls[k][c0];
            const float xv[4] = { xa.x, xa.y, xa.z, xa.w };
            const float wv[4] = { wb.x, wb.y, wb.z, wb.w };
            #pragma unroll
            for (int i = 0; i < 4; ++i)
                #pragma unroll
                for (int j = 0; j < 4; ++j)
                    acc[i][j] = fmaf(xv[i], wv[j], acc[i][j]);
        }
    }

    #pragma unroll
    for (int i = 0; i < 4; ++i) {
        const int pos = tile0 + r0 + i;
        if (pos >= cnt) break;
        const int grow = rowlist[e * BB + pos];
        const float pw = problist[e * BB + pos];
        float* orow = outp + (size_t)grow * ACTD + ctile + c0;
        #pragma unroll
        for (int j = 0; j < 4; ++j)
            atomicAdd(&orow[j], pw * (acc[i][j] + bias[ctile + c0 + j]));
    }
}

__global__ __launch_bounds__(256) void tanh_ep(float* __restrict__ out)
{
    const int i = blockIdx.x * 256 + threadIdx.x;
    float4* p = (float4*)(out + (size_t)BB * ACTD);
    float4 v = p[i];
    v.x = -5.f + 3.5f * (tanhf(v.x) + 1.f);
    v.y = -5.f + 3.5f * (tanhf(v.y) + 1.f);
    v.z = -5.f + 3.5f * (tanhf(v.z) + 1.f);
    v.w = -5.f + 3.5f * (tanhf(v.w) + 1.f);
    p[i] = v;
}

extern "C" void kernel_launch(void* const* d_in, const int* in_sizes, int n_in,
                              void* d_out, int out_size, void* d_ws, size_t ws_size,
                              hipStream_t stream)
{
    const float* x        = (const float*)d_in[0];
    const float* router_w = (const float*)d_in[1];
    const float* router_b = (const float*)d_in[2];
    const float* mean_w   = (const float*)d_in[3];
    const float* mean_b   = (const float*)d_in[4];
    const float* lstd_w   = (const float*)d_in[5];
    const float* lstd_b   = (const float*)d_in[6];

    float* out = (float*)d_out;
    int*    counts   = (int*)d_ws;
    int*    rowlist  = (int*)((char*)d_ws + WS_ROWLIST_OFF);
    float*  problist = (float*)((char*)d_ws + WS_PROBLIST_OFF);
    int*    slot_of  = (int*)((char*)d_ws + WS_SLOT_OFF);
    ushort* xbf      = (ushort*)((char*)d_ws + WS_XBF_OFF);
    ushort* wmbf     = (ushort*)((char*)d_ws + WS_WM_OFF);
    ushort* wlbf     = (ushort*)((char*)d_ws + WS_WL_OFF);
    ushort* partial  = (ushort*)((char*)d_ws + WS_PART_OFF);

    const bool tierA2 = (ws_size >= WS_NEEDED_A2);

    if (tierA2) {
        const int wn4 = NE * ACTD * OBS / 4;
        cvt2_bf16<<<2 * wn4 / 256, 256, 0, stream>>>(mean_w, lstd_w, wmbf, wlbf,
                                                     wn4, counts);

        router_kernel<<<BB / 16, 256, 0, stream>>>(x, router_w, router_b,
                                                   counts, rowlist, problist,
                                                   slot_of, xbf, 1);

        dim3 grid(BB / 64, NE, 4);
        moe_gemm_64<<<grid, 256, 0, stream>>>(xbf, wmbf, wlbf, mean_b, lstd_b,
                                              counts, rowlist, problist,
                                              slot_of, partial);
        combine_kernel<<<BB * 64 / 256, 256, 0, stream>>>(partial, out);
    } else {
        hipMemsetAsync(d_ws, 0, 64, stream);
        hipMemsetAsync(d_out, 0, (size_t)out_size * sizeof(float), stream);
        router_kernel<<<BB / 16, 256, 0, stream>>>(x, router_w, router_b,
                                                   counts, rowlist, problist,
                                                   (int*)nullptr, (ushort*)nullptr, 0);
        dim3 grid(BB / 32, NE, 4);
        moe_gemm_f32<<<grid, 256, 0, stream>>>(x, mean_w, mean_b, lstd_w, lstd_b,
                                               counts, rowlist, problist, out);
        tanh_ep<<<(BB * ACTD / 4) / 256, 256, 0, stream>>>(out);
    }
}